// Round 4
// baseline (189.656 us; speedup 1.0000x reference)
//
#include <hip/hip_runtime.h>
#include <hip/hip_bf16.h>
#include <math.h>

// Delta-rule linear attention, chunked + MFMA bf16, bf16 state buffer.
// B=8, S=4096, D=256, L=64 -> C=64 chunks/batch, 512 chunks total.
// ws: A/H buffer [512][256][256] bf16 in TRANSPOSED [j][i] layout (64 MiB),
//     then P [512] f32.

#define B_ 8
#define S_ 4096
#define D_ 256
#define L_ 64
#define C_ (S_ / L_)
#define BC_ (B_ * C_)
#define STK 66            // u16 stride for transposed [.][s] tiles (==1 mod 32 in u32)

typedef __attribute__((ext_vector_type(8))) short s8v;   // 8 bf16 (4 VGPR)
typedef __attribute__((ext_vector_type(4))) float f4v;   // MFMA acc
typedef unsigned short u16;
typedef unsigned int u32;

__device__ __forceinline__ u32 pk2(float lo, float hi) {  // v_cvt_pk_bf16_f32
  union { __hip_bfloat162 h; u32 u; } cv;
  cv.h = __float22bfloat162_rn(make_float2(lo, hi));
  return cv.u;
}
__device__ __forceinline__ s8v pack8(const float4 a, const float4 b) {
  union { u32 u[4]; s8v v; } r;
  r.u[0] = pk2(a.x, a.y); r.u[1] = pk2(a.z, a.w);
  r.u[2] = pk2(b.x, b.y); r.u[3] = pk2(b.z, b.w);
  return r.v;
}

// ---------------------------------------------------------------------------
// Kernel 1: A[bc][j][i] = sum_s w_s k_s[i] v_s[j]  (bf16, [j][i] layout)
//           P[bc] = prod_s beta_s.
// MFMA: M=i (A-op = w-scaled K^T, reg-cached), N=j (B-op = V^T).
// A written via LDS bounce (KT reuse) -> fully coalesced b128 stores.
// ---------------------------------------------------------------------------
__global__ __launch_bounds__(512, 4) void ks_summary4(
    const float* __restrict__ kg, const float* __restrict__ vg,
    const float* __restrict__ beta, u16* __restrict__ A,
    float* __restrict__ P)
{
  __shared__ float ls[L_];
  __shared__ __align__(16) u16 KT[D_ * STK];   // [i][s]; later: bounce [64][264]
  __shared__ __align__(16) u16 VT[D_ * STK];   // [j][s]

  const int bc = blockIdx.x;
  const int b = bc / C_, c = bc % C_;
  const int tid = threadIdx.x;
  const float* betap = beta + (size_t)b * S_ + (size_t)c * L_;
  const float* kbase = kg + ((size_t)b * S_ + (size_t)c * L_) * D_;
  const float* vbase = vg + ((size_t)b * S_ + (size_t)c * L_) * D_;

  if (tid < 64) {                       // wave0: parallel prefix log2 scan
    float x = log2f(fmaxf(betap[tid], 1e-30f));
#pragma unroll
    for (int off = 1; off < 64; off <<= 1) {
      float y = __shfl_up(x, off);
      if (tid >= off) x += y;
    }
    ls[tid] = x;
    if (tid == 63) P[bc] = exp2f(x);
  }
  __syncthreads();
  const float ltot = ls[63];

  // ---- stage transposed bf16 tiles (conflict-free u32 writes) ----
  {
    const int half = tid >> 8;          // 0: K (w-scaled), 1: V
    const int t2 = tid & 255;
    const int iL = t2 & 7;
    const int s0 = (t2 >> 3) * 2;
    const float* src0 = (half == 0 ? kbase : vbase) + (size_t)s0 * D_;
    const float* src1 = src0 + D_;
    float w0 = 1.f, w1 = 1.f;
    if (half == 0) { w0 = exp2f(ltot - ls[s0]); w1 = exp2f(ltot - ls[s0 + 1]); }
    u16* dst = (half == 0) ? KT : VT;
#pragma unroll
    for (int p = 0; p < 8; ++p) {
      const int i0 = p * 32 + iL * 4;
      float a0[4], a1[4];
      *(float4*)a0 = *(const float4*)(src0 + i0);
      *(float4*)a1 = *(const float4*)(src1 + i0);
#pragma unroll
      for (int u = 0; u < 4; ++u)
        *(u32*)&dst[(i0 + u) * STK + s0] = pk2(a0[u] * w0, a1[u] * w1);
    }
  }
  __syncthreads();

  const int lane = tid & 63, wave = tid >> 6;
  const int quad = lane >> 4, l15 = lane & 15;
  const int i0w = wave * 32;                 // i-strip for this wave

  // cache A-operand (K^T) fragments, then KT becomes the bounce buffer
  s8v af[2][2];
#pragma unroll
  for (int mt = 0; mt < 2; ++mt)
#pragma unroll
    for (int ks = 0; ks < 2; ++ks)
      af[mt][ks] = *(const s8v*)&KT[(i0w + mt * 16 + l15) * STK +
                                    ks * 32 + quad * 8];
  __syncthreads();

  u16* Ab = A + (size_t)bc * D_ * D_;
  u16* BN = KT;                              // bounce: [64 j][264 i-pad]

  for (int ng = 0; ng < 4; ++ng) {           // j-groups of 64
    f4v acc[2][4];
#pragma unroll
    for (int mt = 0; mt < 2; ++mt)
#pragma unroll
      for (int nt = 0; nt < 4; ++nt) acc[mt][nt] = (f4v){0.f, 0.f, 0.f, 0.f};

#pragma unroll
    for (int ks = 0; ks < 2; ++ks) {
      const int so = ks * 32 + quad * 8;
      s8v bv[4];
#pragma unroll
      for (int nt = 0; nt < 4; ++nt)
        bv[nt] = *(const s8v*)&VT[(ng * 64 + nt * 16 + l15) * STK + so];
#pragma unroll
      for (int mt = 0; mt < 2; ++mt)
#pragma unroll
        for (int nt = 0; nt < 4; ++nt)
          acc[mt][nt] = __builtin_amdgcn_mfma_f32_16x16x32_bf16(
              af[mt][ks], bv[nt], acc[mt][nt], 0, 0, 0);
    }
    // C-frags -> bounce (r runs along i: in-lane packing, no shuffles)
#pragma unroll
    for (int mt = 0; mt < 2; ++mt)
#pragma unroll
      for (int nt = 0; nt < 4; ++nt) {
        const int jl = nt * 16 + l15;
        uint2 w;
        w.x = pk2(acc[mt][nt][0], acc[mt][nt][1]);
        w.y = pk2(acc[mt][nt][2], acc[mt][nt][3]);
        *(uint2*)&BN[jl * 264 + i0w + mt * 16 + quad * 4] = w;
      }
    __syncthreads();
    // coalesced copy-out: 64 rows x 512 B, 128 B per wave-instruction
    {
      const int jl = tid >> 3;
      const int il = (tid & 7) * 8;
#pragma unroll
      for (int p = 0; p < 4; ++p) {
        const int iu = il + p * 64;
        *(s8v*)&Ab[(size_t)(ng * 64 + jl) * D_ + iu] =
            *(const s8v*)&BN[jl * 264 + iu];
      }
    }
    __syncthreads();
  }
}

// ---------------------------------------------------------------------------
// Kernel 2: in-place chunk scan (bf16 state, fp32 accumulate), 2-deep
// prefetch. On exit A[bc] holds state ENTERING chunk c.
// ---------------------------------------------------------------------------
__global__ __launch_bounds__(256) void ks_scan4(
    u16* __restrict__ A, const float* __restrict__ P)
{
  const int g = blockIdx.x;
  const int b = g >> 7;                                 // 128 blocks / batch
  const int idx = ((g & 127) << 8) + threadIdx.x;       // u32 unit 0..32767
  u16* base = A + (size_t)b * ((size_t)C_ * D_ * D_) + (size_t)idx * 2;
  const float* Pb = P + b * C_;

  float h0 = 0.f, h1 = 0.f;
  u32 cur = *(const u32*)base;
  u32 nx = *(const u32*)(base + (size_t)(D_ * D_));
  float pc = Pb[0], pn = Pb[1];
#pragma unroll 4
  for (int c = 0; c < C_; ++c) {
    u16* p = base + (size_t)c * (D_ * D_);
    u32 n2 = 0; float p2 = 0.f;
    if (c + 2 < C_) {
      n2 = *(const u32*)(p + 2 * (size_t)(D_ * D_));
      p2 = Pb[c + 2];
    }
    const float a0 = __uint_as_float(cur << 16);
    const float a1 = __uint_as_float(cur & 0xFFFF0000u);
    *(u32*)p = pk2(h0, h1);
    h0 = fmaf(pc, h0, a0);
    h1 = fmaf(pc, h1, a1);
    cur = nx; pc = pn; nx = n2; pn = p2;
  }
}

// ---------------------------------------------------------------------------
// Kernel 3: O = Tm @ V + diag(c) Q @ H.   512 thr / 8 waves.
//  phase A (M=s, N=t): Tm[t][s] written as packed uint2.
//  phase B (M=j, N=t): A-ops VT / H[j][i](global), B-ops Tm / QB.
//  Epilogue: float4 stores, 64 B row segments.
// ---------------------------------------------------------------------------
__global__ __launch_bounds__(512, 4) void ks_output4(
    const float* __restrict__ qg, const float* __restrict__ kg,
    const float* __restrict__ vg, const float* __restrict__ beta,
    const u16* __restrict__ Hg, float* __restrict__ outg)
{
  __shared__ float ls[L_];
  __shared__ float cv[L_];
  __shared__ __align__(16) u16 QB[L_ * 264];     // [t][d] bf16
  __shared__ __align__(16) u16 UN[L_ * 264];     // KB[64][264] then VT[256][66]
  __shared__ __align__(16) u16 Tm[L_ * 72];      // [t][s] bf16

  const int bc = blockIdx.x;
  const int b = bc / C_, c = bc % C_;
  const int tid = threadIdx.x;
  const float* betap = beta + (size_t)b * S_ + (size_t)c * L_;
  const float* qbase = qg + ((size_t)b * S_ + (size_t)c * L_) * D_;
  const float* kbase = kg + ((size_t)b * S_ + (size_t)c * L_) * D_;
  const float* vbase = vg + ((size_t)b * S_ + (size_t)c * L_) * D_;
  const u16* Hb = Hg + (size_t)bc * D_ * D_;

  if (tid < 64) {                       // wave0: beta prefix scan
    float x = log2f(fmaxf(betap[tid], 1e-30f));
#pragma unroll
    for (int off = 1; off < 64; off <<= 1) {
      float y = __shfl_up(x, off);
      if (tid >= off) x += y;
    }
    ls[tid] = x;
  }

  // ---- stage QB (half 0) and KB (half 1), row-major bf16, b128 writes ----
  {
    const int half = tid >> 8;
    const int t2 = tid & 255;
    const int t = t2 >> 2;
    const int cg = (t2 & 3) * 8;
    const float* src = (half == 0 ? qbase : kbase) + (size_t)t * D_ + cg;
    u16* dst = (half == 0) ? QB : UN;
#pragma unroll
    for (int p = 0; p < 8; ++p) {
      const s8v pk = pack8(*(const float4*)(src + p * 32),
                           *(const float4*)(src + p * 32 + 4));
      *(s8v*)&dst[t * 264 + cg + p * 32] = pk;
    }
  }
  __syncthreads();
  if (tid < 64) cv[tid] = exp2f(ls[tid]);   // c_t

  const int lane = tid & 63, wave = tid >> 6;
  const int quad = lane >> 4, l15 = lane & 15;

  // ---- phase A: T = Q K^T with M=s, N=t.  wave: s-tile (w&3), t-strip w>>2.
  {
    const int mA = (wave & 3) * 16;     // s-tile base
    const int nB = (wave >> 2) * 32;    // t-strip base (2 tiles)
    f4v accA[2];
#pragma unroll
    for (int i = 0; i < 2; ++i) accA[i] = (f4v){0.f, 0.f, 0.f, 0.f};
#pragma unroll
    for (int kd = 0; kd < 8; ++kd) {
      const int d0 = kd * 32 + quad * 8;
      const s8v af = *(const s8v*)&UN[(mA + l15) * 264 + d0];   // K rows
#pragma unroll
      for (int i = 0; i < 2; ++i) {
        const s8v bf = *(const s8v*)&QB[(nB + i * 16 + l15) * 264 + d0];
        accA[i] = __builtin_amdgcn_mfma_f32_16x16x32_bf16(af, bf, accA[i],
                                                          0, 0, 0);
      }
    }
    // rows = s (quad*4+r), cols = t (l15): pack 4 s-values per lane
#pragma unroll
    for (int i = 0; i < 2; ++i) {
      const int t = nB + i * 16 + l15;
      const float lt = ls[t];
      const int s0 = mA + quad * 4;
      float v[4];
#pragma unroll
      for (int r = 0; r < 4; ++r) {
        const int s = s0 + r;
        v[r] = (s <= t) ? accA[i][r] * exp2f(lt - ls[s]) : 0.f;
      }
      uint2 w;
      w.x = pk2(v[0], v[1]);
      w.y = pk2(v[2], v[3]);
      *(uint2*)&Tm[t * 72 + s0] = w;
    }
  }
  __syncthreads();   // Tm ready; KB dead

  // ---- stage V^T bf16 over KB's space ----
  u16* VT = UN;
  {
    const int iL = tid & 15;
    const int s0 = (tid >> 4) * 2;
#pragma unroll
    for (int p = 0; p < 4; ++p) {
      const int i0 = p * 64 + iL * 4;
      float a0[4], a1[4];
      *(float4*)a0 = *(const float4*)(vbase + (size_t)s0 * D_ + i0);
      *(float4*)a1 = *(const float4*)(vbase + (size_t)(s0 + 1) * D_ + i0);
#pragma unroll
      for (int u = 0; u < 4; ++u)
        *(u32*)&VT[(i0 + u) * STK + s0] = pk2(a0[u], a1[u]);
    }
  }
  __syncthreads();

  // ---- phase B: M=j (strip of 32 per wave), N=t (64) ----
  const int j0w = wave * 32;
  f4v accS[2][4], accH[2][4];
#pragma unroll
  for (int mt = 0; mt < 2; ++mt)
#pragma unroll
    for (int nt = 0; nt < 4; ++nt) {
      accS[mt][nt] = (f4v){0.f, 0.f, 0.f, 0.f};
      accH[mt][nt] = (f4v){0.f, 0.f, 0.f, 0.f};
    }

  // Tm @ V: A-op = VT[j][s], B-op = Tm[t][s]
#pragma unroll
  for (int ks = 0; ks < 2; ++ks) {
    const int so = ks * 32 + quad * 8;
    s8v af[2], bf[4];
#pragma unroll
    for (int mt = 0; mt < 2; ++mt)
      af[mt] = *(const s8v*)&VT[(j0w + mt * 16 + l15) * STK + so];
#pragma unroll
    for (int nt = 0; nt < 4; ++nt)
      bf[nt] = *(const s8v*)&Tm[(nt * 16 + l15) * 72 + so];
#pragma unroll
    for (int mt = 0; mt < 2; ++mt)
#pragma unroll
      for (int nt = 0; nt < 4; ++nt)
        accS[mt][nt] = __builtin_amdgcn_mfma_f32_16x16x32_bf16(
            af[mt], bf[nt], accS[mt][nt], 0, 0, 0);
  }

  // Q @ H: A-op = H[j][i] (global bf16), B-op = QB[t][i]
#pragma unroll
  for (int ks = 0; ks < 8; ++ks) {
    const int io = ks * 32 + quad * 8;
    s8v af[2], bf[4];
#pragma unroll
    for (int mt = 0; mt < 2; ++mt)
      af[mt] = *(const s8v*)(Hb + (size_t)(j0w + mt * 16 + l15) * D_ + io);
#pragma unroll
    for (int nt = 0; nt < 4; ++nt)
      bf[nt] = *(const s8v*)&QB[(nt * 16 + l15) * 264 + io];
#pragma unroll
    for (int mt = 0; mt < 2; ++mt)
#pragma unroll
      for (int nt = 0; nt < 4; ++nt)
        accH[mt][nt] = __builtin_amdgcn_mfma_f32_16x16x32_bf16(
            af[mt], bf[nt], accH[mt][nt], 0, 0, 0);
  }

  // epilogue: O[t][j] = accS + c_t * accH ; r runs along j -> float4 stores
  float* ob = outg + ((size_t)b * S_ + (size_t)c * L_) * D_;
#pragma unroll
  for (int mt = 0; mt < 2; ++mt)
#pragma unroll
    for (int nt = 0; nt < 4; ++nt) {
      const int t = nt * 16 + l15;
      const float ct = cv[t];
      const int j0 = j0w + mt * 16 + quad * 4;
      float4 o;
      o.x = accS[mt][nt][0] + ct * accH[mt][nt][0];
      o.y = accS[mt][nt][1] + ct * accH[mt][nt][1];
      o.z = accS[mt][nt][2] + ct * accH[mt][nt][2];
      o.w = accS[mt][nt][3] + ct * accH[mt][nt][3];
      *(float4*)(ob + (size_t)t * D_ + j0) = o;
    }
}

// ---------------------------------------------------------------------------
extern "C" void kernel_launch(void* const* d_in, const int* in_sizes, int n_in,
                              void* d_out, int out_size, void* d_ws,
                              size_t ws_size, hipStream_t stream) {
  const float* q = (const float*)d_in[0];
  const float* k = (const float*)d_in[1];
  const float* v = (const float*)d_in[2];
  const float* beta = (const float*)d_in[3];
  float* out = (float*)d_out;

  u16* A = (u16*)d_ws;                                   // 64 MiB bf16 state
  float* P = (float*)((char*)d_ws + (size_t)BC_ * D_ * D_ * sizeof(u16));

  ks_summary4<<<dim3(BC_), dim3(512), 0, stream>>>(k, v, beta, A, P);
  ks_scan4<<<dim3(1024), dim3(256), 0, stream>>>(A, P);
  ks_output4<<<dim3(BC_), dim3(512), 0, stream>>>(q, k, v, beta, A, out);
}

// Round 5
// 175.463 us; speedup vs baseline: 1.0809x; 1.0809x over previous
//
#include <hip/hip_runtime.h>
#include <hip/hip_bf16.h>
#include <math.h>

// Delta-rule linear attention, chunked + MFMA bf16, bf16 state buffer.
// B=8, S=4096, D=256, L=128 -> C=32 chunks/batch, 256 chunks total.
// ws: A/H buffer [256][256][256] bf16 in TRANSPOSED [j][i] layout (33.5 MB),
//     then P [256] f32.

#define B_ 8
#define S_ 4096
#define D_ 256
#define L_ 128
#define C_ (S_ / L_)      // 32
#define BC_ (B_ * C_)     // 256
#define STK 66            // u16 stride for transposed [.][s64] tiles

typedef __attribute__((ext_vector_type(8))) short s8v;   // 8 bf16 (4 VGPR)
typedef __attribute__((ext_vector_type(4))) float f4v;   // MFMA acc
typedef unsigned short u16;
typedef unsigned int u32;

__device__ __forceinline__ u32 pk2(float lo, float hi) {  // v_cvt_pk_bf16_f32
  union { __hip_bfloat162 h; u32 u; } cv;
  cv.h = __float22bfloat162_rn(make_float2(lo, hi));
  return cv.u;
}
__device__ __forceinline__ s8v pack8(const float4 a, const float4 b) {
  union { u32 u[4]; s8v v; } r;
  r.u[0] = pk2(a.x, a.y); r.u[1] = pk2(a.z, a.w);
  r.u[2] = pk2(b.x, b.y); r.u[3] = pk2(b.z, b.w);
  return r.v;
}

// 128-step prefix log2(beta) scan by wave 0 into ls[]; returns nothing.
__device__ __forceinline__ void beta_scan128(const float* betap, float* ls,
                                             int tid) {
  if (tid < 64) {
    float x = log2f(fmaxf(betap[tid], 1e-30f));
#pragma unroll
    for (int off = 1; off < 64; off <<= 1) {
      float y = __shfl_up(x, off);
      if (tid >= off) x += y;
    }
    ls[tid] = x;
    const float tot0 = __shfl(x, 63);
    float z = log2f(fmaxf(betap[64 + tid], 1e-30f));
#pragma unroll
    for (int off = 1; off < 64; off <<= 1) {
      float y = __shfl_up(z, off);
      if (tid >= off) z += y;
    }
    ls[64 + tid] = z + tot0;
  }
}

// ---------------------------------------------------------------------------
// Kernel 1: A[bc][j][i] = sum_{s<128} w_s k_s[i] v_s[j]  (bf16, [j][i])
//           P[bc] = prod_s beta_s.
// MFMA: M=i (A-op = w-scaled K^T, reg-cached across both s-halves),
//       N=j (B-op = V^T staged over K^T's LDS).  A written via LDS bounce.
// ---------------------------------------------------------------------------
__global__ __launch_bounds__(512, 2) void ks_summary5(
    const float* __restrict__ kg, const float* __restrict__ vg,
    const float* __restrict__ beta, u16* __restrict__ A,
    float* __restrict__ P)
{
  __shared__ float ls[L_];
  __shared__ __align__(16) u16 U[2][256 * STK];   // K^T halves, then V^T halves
  __shared__ __align__(16) u16 BN[64 * 264];      // bounce [64 j][264 i-pad]

  const int bc = blockIdx.x;
  const int b = bc / C_, c = bc % C_;
  const int tid = threadIdx.x;
  const float* betap = beta + (size_t)b * S_ + (size_t)c * L_;
  const float* kbase = kg + ((size_t)b * S_ + (size_t)c * L_) * D_;
  const float* vbase = vg + ((size_t)b * S_ + (size_t)c * L_) * D_;

  beta_scan128(betap, ls, tid);
  __syncthreads();
  const float ltot = ls[L_ - 1];
  if (tid == 0) P[bc] = exp2f(ltot);

  const int hh = tid >> 8;            // s-half this thread stages
  const int t2 = tid & 255;
  const int iLs = t2 & 7;
  const int s0s = (t2 >> 3) * 2;      // local s-pair base 0..62
  const int sg = hh * 64 + s0s;       // global s

  // ---- stage w-scaled K^T (both halves) ----
  {
    const float* src0 = kbase + (size_t)sg * D_;
    const float* src1 = src0 + D_;
    const float w0 = exp2f(ltot - ls[sg]);
    const float w1 = exp2f(ltot - ls[sg + 1]);
    u16* dst = U[hh];
#pragma unroll
    for (int p = 0; p < 8; ++p) {
      const int i0 = p * 32 + iLs * 4;
      float a0[4], a1[4];
      *(float4*)a0 = *(const float4*)(src0 + i0);
      *(float4*)a1 = *(const float4*)(src1 + i0);
#pragma unroll
      for (int u = 0; u < 4; ++u)
        *(u32*)&dst[(i0 + u) * STK + s0s] = pk2(a0[u] * w0, a1[u] * w1);
    }
  }
  __syncthreads();

  const int lane = tid & 63, wave = tid >> 6;
  const int quad = lane >> 4, l15 = lane & 15;
  const int i0w = wave * 32;          // i-strip for this wave

  // cache A-operand (K^T) fragments covering all 4 k-steps (s=128)
  s8v af[2][4];
#pragma unroll
  for (int mt = 0; mt < 2; ++mt)
#pragma unroll
    for (int ks = 0; ks < 4; ++ks)
      af[mt][ks] = *(const s8v*)&U[ks >> 1][(i0w + mt * 16 + l15) * STK +
                                            (ks & 1) * 32 + quad * 8];
  __syncthreads();

  // ---- stage V^T over K^T's LDS ----
  {
    const float* src0 = vbase + (size_t)sg * D_;
    const float* src1 = src0 + D_;
    u16* dst = U[hh];
#pragma unroll
    for (int p = 0; p < 8; ++p) {
      const int i0 = p * 32 + iLs * 4;
      float a0[4], a1[4];
      *(float4*)a0 = *(const float4*)(src0 + i0);
      *(float4*)a1 = *(const float4*)(src1 + i0);
#pragma unroll
      for (int u = 0; u < 4; ++u)
        *(u32*)&dst[(i0 + u) * STK + s0s] = pk2(a0[u], a1[u]);
    }
  }
  __syncthreads();

  u16* Ab = A + (size_t)bc * D_ * D_;

  for (int ng = 0; ng < 4; ++ng) {    // j-groups of 64
    f4v acc[2][4];
#pragma unroll
    for (int mt = 0; mt < 2; ++mt)
#pragma unroll
      for (int nt = 0; nt < 4; ++nt) acc[mt][nt] = (f4v){0.f, 0.f, 0.f, 0.f};

#pragma unroll
    for (int ks = 0; ks < 4; ++ks) {
      const int so = (ks & 1) * 32 + quad * 8;
      s8v bv[4];
#pragma unroll
      for (int nt = 0; nt < 4; ++nt)
        bv[nt] = *(const s8v*)&U[ks >> 1][(ng * 64 + nt * 16 + l15) * STK + so];
#pragma unroll
      for (int mt = 0; mt < 2; ++mt)
#pragma unroll
        for (int nt = 0; nt < 4; ++nt)
          acc[mt][nt] = __builtin_amdgcn_mfma_f32_16x16x32_bf16(
              af[mt][ks], bv[nt], acc[mt][nt], 0, 0, 0);
    }
    // C-frags -> bounce (r runs along i: in-lane packing)
#pragma unroll
    for (int mt = 0; mt < 2; ++mt)
#pragma unroll
      for (int nt = 0; nt < 4; ++nt) {
        const int jl = nt * 16 + l15;
        uint2 w;
        w.x = pk2(acc[mt][nt][0], acc[mt][nt][1]);
        w.y = pk2(acc[mt][nt][2], acc[mt][nt][3]);
        *(uint2*)&BN[jl * 264 + i0w + mt * 16 + quad * 4] = w;
      }
    __syncthreads();
    // coalesced copy-out: 64 rows x 512 B
    {
      const int jl = tid >> 3;
      const int il = (tid & 7) * 8;
#pragma unroll
      for (int p = 0; p < 4; ++p) {
        const int iu = il + p * 64;
        *(s8v*)&Ab[(size_t)(ng * 64 + jl) * D_ + iu] =
            *(const s8v*)&BN[jl * 264 + iu];
      }
    }
    __syncthreads();
  }
}

// ---------------------------------------------------------------------------
// Kernel 2: in-place chunk scan (bf16 state, fp32 accumulate), 2-deep
// prefetch, 32 steps. On exit A[bc] holds state ENTERING chunk c.
// ---------------------------------------------------------------------------
__global__ __launch_bounds__(256) void ks_scan5(
    u16* __restrict__ A, const float* __restrict__ P)
{
  const int g = blockIdx.x;
  const int b = g >> 7;                                 // 128 blocks / batch
  const int idx = ((g & 127) << 8) + threadIdx.x;       // u32 unit 0..32767
  u16* base = A + (size_t)b * ((size_t)C_ * D_ * D_) + (size_t)idx * 2;
  const float* Pb = P + b * C_;

  float h0 = 0.f, h1 = 0.f;
  u32 cur = *(const u32*)base;
  u32 nx = *(const u32*)(base + (size_t)(D_ * D_));
  float pc = Pb[0], pn = Pb[1];
#pragma unroll 4
  for (int c = 0; c < C_; ++c) {
    u16* p = base + (size_t)c * (D_ * D_);
    u32 n2 = 0; float p2 = 0.f;
    if (c + 2 < C_) {
      n2 = *(const u32*)(p + 2 * (size_t)(D_ * D_));
      p2 = Pb[c + 2];
    }
    const float a0 = __uint_as_float(cur << 16);
    const float a1 = __uint_as_float(cur & 0xFFFF0000u);
    *(u32*)p = pk2(h0, h1);
    h0 = fmaf(pc, h0, a0);
    h1 = fmaf(pc, h1, a1);
    cur = nx; pc = pn; nx = n2; pn = p2;
  }
}

// ---------------------------------------------------------------------------
// Kernel 3: O = Tm @ V + diag(c) Q @ H.   512 thr / 8 waves, L=128.
//  phase A (M=s, N=t): K-frags from global (each row read once), Q from LDS.
//  QH first into acc, scale by c_t (t is the lane dim), then TmV accumulates
//  into the SAME acc with V^T staged per s-half.
// ---------------------------------------------------------------------------
__global__ __launch_bounds__(512, 2) void ks_output5(
    const float* __restrict__ qg, const float* __restrict__ kg,
    const float* __restrict__ vg, const float* __restrict__ beta,
    const u16* __restrict__ Hg, float* __restrict__ outg)
{
  __shared__ float ls[L_];
  __shared__ float cv[L_];
  __shared__ __align__(16) u16 QB[L_ * 264];     // [t][d] bf16   (67.6 KB)
  __shared__ __align__(16) u16 Tm[L_ * 136];     // [t][s] bf16   (34.8 KB)
  __shared__ __align__(16) u16 VT[256 * STK];    // [j][s-half]   (33.8 KB)

  const int bc = blockIdx.x;
  const int b = bc / C_, c = bc % C_;
  const int tid = threadIdx.x;
  const float* betap = beta + (size_t)b * S_ + (size_t)c * L_;
  const float* qbase = qg + ((size_t)b * S_ + (size_t)c * L_) * D_;
  const float* kbase = kg + ((size_t)b * S_ + (size_t)c * L_) * D_;
  const float* vbase = vg + ((size_t)b * S_ + (size_t)c * L_) * D_;
  const u16* Hb = Hg + (size_t)bc * D_ * D_;

  beta_scan128(betap, ls, tid);

  // ---- stage QB row-major bf16 ----
  {
    const int t = tid >> 2;
    const int cg = (tid & 3) * 8;
    const float* src = qbase + (size_t)t * D_ + cg;
#pragma unroll
    for (int p = 0; p < 8; ++p) {
      const s8v pk = pack8(*(const float4*)(src + p * 32),
                           *(const float4*)(src + p * 32 + 4));
      *(s8v*)&QB[t * 264 + cg + p * 32] = pk;
    }
  }
  __syncthreads();
  if (tid < L_) cv[tid] = exp2f(ls[tid]);   // c_t (visible after later syncs)

  const int lane = tid & 63, wave = tid >> 6;
  const int quad = lane >> 4, l15 = lane & 15;

  // ---- phase A: T = Q K^T.  wave w owns s-tile w; loops all 8 t-tiles ----
  {
    const int mA = wave * 16;           // s-tile base
    f4v accA[8];
#pragma unroll
    for (int i = 0; i < 8; ++i) accA[i] = (f4v){0.f, 0.f, 0.f, 0.f};
#pragma unroll
    for (int kd = 0; kd < 8; ++kd) {
      const int d0 = kd * 32 + quad * 8;
      const float* krow = kbase + (size_t)(mA + l15) * D_ + d0;
      const s8v af = pack8(*(const float4*)krow, *(const float4*)(krow + 4));
#pragma unroll
      for (int nt = 0; nt < 8; ++nt) {
        const s8v bf = *(const s8v*)&QB[(nt * 16 + l15) * 264 + d0];
        accA[nt] = __builtin_amdgcn_mfma_f32_16x16x32_bf16(af, bf, accA[nt],
                                                           0, 0, 0);
      }
    }
    // rows = s (quad*4+r), cols = t (l15): mask+decay, pack s-pairs
#pragma unroll
    for (int nt = 0; nt < 8; ++nt) {
      const int t = nt * 16 + l15;
      const float lt = ls[t];
      const int s0 = mA + quad * 4;
      float v[4];
#pragma unroll
      for (int r = 0; r < 4; ++r) {
        const int s = s0 + r;
        v[r] = (s <= t) ? accA[nt][r] * exp2f(lt - ls[s]) : 0.f;
      }
      uint2 w;
      w.x = pk2(v[0], v[1]);
      w.y = pk2(v[2], v[3]);
      *(uint2*)&Tm[t * 136 + s0] = w;
    }
  }
  __syncthreads();   // Tm ready

  // ---- Q @ H into acc (A-op = H[j][i] global bf16, B-op = QB) ----
  const int j0w = wave * 32;
  f4v acc[2][8];
#pragma unroll
  for (int mt = 0; mt < 2; ++mt)
#pragma unroll
    for (int nt = 0; nt < 8; ++nt) acc[mt][nt] = (f4v){0.f, 0.f, 0.f, 0.f};

#pragma unroll
  for (int ks = 0; ks < 8; ++ks) {
    const int io = ks * 32 + quad * 8;
    s8v af[2], bf[8];
#pragma unroll
    for (int mt = 0; mt < 2; ++mt)
      af[mt] = *(const s8v*)(Hb + (size_t)(j0w + mt * 16 + l15) * D_ + io);
#pragma unroll
    for (int nt = 0; nt < 8; ++nt)
      bf[nt] = *(const s8v*)&QB[(nt * 16 + l15) * 264 + io];
#pragma unroll
    for (int mt = 0; mt < 2; ++mt)
#pragma unroll
      for (int nt = 0; nt < 8; ++nt)
        acc[mt][nt] = __builtin_amdgcn_mfma_f32_16x16x32_bf16(
            af[mt], bf[nt], acc[mt][nt], 0, 0, 0);
  }
  // scale by c_t  (t = nt*16 + l15 is constant per lane per nt)
#pragma unroll
  for (int nt = 0; nt < 8; ++nt) {
    const float ct = cv[nt * 16 + l15];
#pragma unroll
    for (int mt = 0; mt < 2; ++mt) {
      acc[mt][nt][0] *= ct; acc[mt][nt][1] *= ct;
      acc[mt][nt][2] *= ct; acc[mt][nt][3] *= ct;
    }
  }

  // ---- Tm @ V, V^T staged per s-half over VT ----
#pragma unroll
  for (int h = 0; h < 2; ++h) {
    __syncthreads();   // protect VT reuse
    {
      const int iL = tid & 15;
      const int s0 = ((tid >> 4) & 31) * 2;
      const float* src0 = vbase + (size_t)(h * 64 + s0) * D_;
      const float* src1 = src0 + D_;
#pragma unroll
      for (int p = 0; p < 4; ++p) {
        const int i0 = p * 64 + iL * 4;
        float a0[4], a1[4];
        *(float4*)a0 = *(const float4*)(src0 + i0);
        *(float4*)a1 = *(const float4*)(src1 + i0);
#pragma unroll
        for (int u = 0; u < 4; ++u)
          *(u32*)&VT[(i0 + u) * STK + s0] = pk2(a0[u], a1[u]);
      }
    }
    __syncthreads();
#pragma unroll
    for (int ks = 0; ks < 2; ++ks) {
      const int so = ks * 32 + quad * 8;
      s8v af[2], bf[8];
#pragma unroll
      for (int mt = 0; mt < 2; ++mt)
        af[mt] = *(const s8v*)&VT[(j0w + mt * 16 + l15) * STK + so];
#pragma unroll
      for (int nt = 0; nt < 8; ++nt)
        bf[nt] = *(const s8v*)&Tm[(nt * 16 + l15) * 136 + h * 64 + so];
#pragma unroll
      for (int mt = 0; mt < 2; ++mt)
#pragma unroll
        for (int nt = 0; nt < 8; ++nt)
          acc[mt][nt] = __builtin_amdgcn_mfma_f32_16x16x32_bf16(
              af[mt], bf[nt], acc[mt][nt], 0, 0, 0);
    }
  }

  // epilogue: float4 stores (r runs along j)
  float* ob = outg + ((size_t)b * S_ + (size_t)c * L_) * D_;
#pragma unroll
  for (int mt = 0; mt < 2; ++mt)
#pragma unroll
    for (int nt = 0; nt < 8; ++nt) {
      const int t = nt * 16 + l15;
      const int j0 = j0w + mt * 16 + quad * 4;
      float4 o;
      o.x = acc[mt][nt][0]; o.y = acc[mt][nt][1];
      o.z = acc[mt][nt][2]; o.w = acc[mt][nt][3];
      *(float4*)(ob + (size_t)t * D_ + j0) = o;
    }
}

// ---------------------------------------------------------------------------
extern "C" void kernel_launch(void* const* d_in, const int* in_sizes, int n_in,
                              void* d_out, int out_size, void* d_ws,
                              size_t ws_size, hipStream_t stream) {
  const float* q = (const float*)d_in[0];
  const float* k = (const float*)d_in[1];
  const float* v = (const float*)d_in[2];
  const float* beta = (const float*)d_in[3];
  float* out = (float*)d_out;

  u16* A = (u16*)d_ws;                                   // 33.5 MB bf16 state
  float* P = (float*)((char*)d_ws + (size_t)BC_ * D_ * D_ * sizeof(u16));

  ks_summary5<<<dim3(BC_), dim3(512), 0, stream>>>(k, v, beta, A, P);
  ks_scan5<<<dim3(1024), dim3(256), 0, stream>>>(A, P);
  ks_output5<<<dim3(BC_), dim3(512), 0, stream>>>(q, k, v, beta, A, out);
}

// Round 6
// 171.996 us; speedup vs baseline: 1.1027x; 1.0202x over previous
//
#include <hip/hip_runtime.h>
#include <hip/hip_bf16.h>
#include <math.h>

// Delta-rule linear attention, chunked + MFMA bf16, bf16 state buffer.
// B=8, S=4096, D=256, L=128 -> C=32 chunks/batch, 256 chunks total.
// ws: A/H buffer [256][256][256] bf16 in TRANSPOSED [j][i] layout (33.5 MB),
//     then P [256] f32.

#define B_ 8
#define S_ 4096
#define D_ 256
#define L_ 128
#define C_ (S_ / L_)      // 32
#define BC_ (B_ * C_)     // 256
#define STK 66            // u16 stride for transposed [.][s64] tiles

typedef __attribute__((ext_vector_type(8))) short s8v;   // 8 bf16 (4 VGPR)
typedef __attribute__((ext_vector_type(4))) float f4v;   // MFMA acc
typedef unsigned short u16;
typedef unsigned int u32;

__device__ __forceinline__ u32 pk2(float lo, float hi) {  // v_cvt_pk_bf16_f32
  union { __hip_bfloat162 h; u32 u; } cv;
  cv.h = __float22bfloat162_rn(make_float2(lo, hi));
  return cv.u;
}
__device__ __forceinline__ s8v pack8(const float4 a, const float4 b) {
  union { u32 u[4]; s8v v; } r;
  r.u[0] = pk2(a.x, a.y); r.u[1] = pk2(a.z, a.w);
  r.u[2] = pk2(b.x, b.y); r.u[3] = pk2(b.z, b.w);
  return r.v;
}

// 128-step prefix log2(beta) scan by wave 0 into ls[].
__device__ __forceinline__ void beta_scan128(const float* betap, float* ls,
                                             int tid) {
  if (tid < 64) {
    float x = log2f(fmaxf(betap[tid], 1e-30f));
#pragma unroll
    for (int off = 1; off < 64; off <<= 1) {
      float y = __shfl_up(x, off);
      if (tid >= off) x += y;
    }
    ls[tid] = x;
    const float tot0 = __shfl(x, 63);
    float z = log2f(fmaxf(betap[64 + tid], 1e-30f));
#pragma unroll
    for (int off = 1; off < 64; off <<= 1) {
      float y = __shfl_up(z, off);
      if (tid >= off) z += y;
    }
    ls[64 + tid] = z + tot0;
  }
}

// ---------------------------------------------------------------------------
// Kernel 1: A[bc][j][i] = sum_{s<128} w_s k_s[i] v_s[j]  (bf16, [j][i])
//           P[bc] = prod_s beta_s.
// ---------------------------------------------------------------------------
__global__ __launch_bounds__(512, 2) void ks_summary6(
    const float* __restrict__ kg, const float* __restrict__ vg,
    const float* __restrict__ beta, u16* __restrict__ A,
    float* __restrict__ P)
{
  __shared__ float ls[L_];
  __shared__ __align__(16) u16 U[2][256 * STK];   // K^T halves, then V^T halves
  __shared__ __align__(16) u16 BN[64 * 264];      // bounce [64 j][264 i-pad]

  const int bc = blockIdx.x;
  const int b = bc / C_, c = bc % C_;
  const int tid = threadIdx.x;
  const float* betap = beta + (size_t)b * S_ + (size_t)c * L_;
  const float* kbase = kg + ((size_t)b * S_ + (size_t)c * L_) * D_;
  const float* vbase = vg + ((size_t)b * S_ + (size_t)c * L_) * D_;

  beta_scan128(betap, ls, tid);
  __syncthreads();
  const float ltot = ls[L_ - 1];
  if (tid == 0) P[bc] = exp2f(ltot);

  const int hh = tid >> 8;            // s-half this thread stages
  const int t2 = tid & 255;
  const int iLs = t2 & 7;
  const int s0s = (t2 >> 3) * 2;      // local s-pair base 0..62
  const int sg = hh * 64 + s0s;       // global s

  // ---- stage w-scaled K^T (both halves) ----
  {
    const float* src0 = kbase + (size_t)sg * D_;
    const float* src1 = src0 + D_;
    const float w0 = exp2f(ltot - ls[sg]);
    const float w1 = exp2f(ltot - ls[sg + 1]);
    u16* dst = U[hh];
#pragma unroll
    for (int p = 0; p < 8; ++p) {
      const int i0 = p * 32 + iLs * 4;
      float a0[4], a1[4];
      *(float4*)a0 = *(const float4*)(src0 + i0);
      *(float4*)a1 = *(const float4*)(src1 + i0);
#pragma unroll
      for (int u = 0; u < 4; ++u)
        *(u32*)&dst[(i0 + u) * STK + s0s] = pk2(a0[u] * w0, a1[u] * w1);
    }
  }
  __syncthreads();

  const int lane = tid & 63, wave = tid >> 6;
  const int quad = lane >> 4, l15 = lane & 15;
  const int i0w = wave * 32;          // i-strip for this wave

  // cache A-operand (K^T) fragments covering all 4 k-steps (s=128)
  s8v af[2][4];
#pragma unroll
  for (int mt = 0; mt < 2; ++mt)
#pragma unroll
    for (int ks = 0; ks < 4; ++ks)
      af[mt][ks] = *(const s8v*)&U[ks >> 1][(i0w + mt * 16 + l15) * STK +
                                            (ks & 1) * 32 + quad * 8];
  __syncthreads();

  // ---- stage V^T over K^T's LDS ----
  {
    const float* src0 = vbase + (size_t)sg * D_;
    const float* src1 = src0 + D_;
    u16* dst = U[hh];
#pragma unroll
    for (int p = 0; p < 8; ++p) {
      const int i0 = p * 32 + iLs * 4;
      float a0[4], a1[4];
      *(float4*)a0 = *(const float4*)(src0 + i0);
      *(float4*)a1 = *(const float4*)(src1 + i0);
#pragma unroll
      for (int u = 0; u < 4; ++u)
        *(u32*)&dst[(i0 + u) * STK + s0s] = pk2(a0[u], a1[u]);
    }
  }
  __syncthreads();

  u16* Ab = A + (size_t)bc * D_ * D_;

  for (int ng = 0; ng < 4; ++ng) {    // j-groups of 64
    f4v acc[2][4];
#pragma unroll
    for (int mt = 0; mt < 2; ++mt)
#pragma unroll
      for (int nt = 0; nt < 4; ++nt) acc[mt][nt] = (f4v){0.f, 0.f, 0.f, 0.f};

#pragma unroll
    for (int ks = 0; ks < 4; ++ks) {
      const int so = (ks & 1) * 32 + quad * 8;
      s8v bv[4];
#pragma unroll
      for (int nt = 0; nt < 4; ++nt)
        bv[nt] = *(const s8v*)&U[ks >> 1][(ng * 64 + nt * 16 + l15) * STK + so];
#pragma unroll
      for (int mt = 0; mt < 2; ++mt)
#pragma unroll
        for (int nt = 0; nt < 4; ++nt)
          acc[mt][nt] = __builtin_amdgcn_mfma_f32_16x16x32_bf16(
              af[mt][ks], bv[nt], acc[mt][nt], 0, 0, 0);
    }
    // C-frags -> bounce (r runs along i: in-lane packing)
#pragma unroll
    for (int mt = 0; mt < 2; ++mt)
#pragma unroll
      for (int nt = 0; nt < 4; ++nt) {
        const int jl = nt * 16 + l15;
        uint2 w;
        w.x = pk2(acc[mt][nt][0], acc[mt][nt][1]);
        w.y = pk2(acc[mt][nt][2], acc[mt][nt][3]);
        *(uint2*)&BN[jl * 264 + i0w + mt * 16 + quad * 4] = w;
      }
    __syncthreads();
    // coalesced copy-out: 64 rows x 512 B
    {
      const int jl = tid >> 3;
      const int il = (tid & 7) * 8;
#pragma unroll
      for (int p = 0; p < 4; ++p) {
        const int iu = il + p * 64;
        *(s8v*)&Ab[(size_t)(ng * 64 + jl) * D_ + iu] =
            *(const s8v*)&BN[jl * 264 + iu];
      }
    }
    __syncthreads();
  }
}

// ---------------------------------------------------------------------------
// Kernel 2: register-batched chunk scan. Each thread owns a uint2 (4 elems);
// loads ALL 32 chunk values (independent, fully pipelined), runs the
// recurrence in registers, stores all 32. On exit A[bc] = state ENTERING c.
// ---------------------------------------------------------------------------
__global__ __launch_bounds__(256) void ks_scan6(
    u16* __restrict__ A, const float* __restrict__ P)
{
  const int g = blockIdx.x;                       // 512 blocks
  const int b = g >> 6;                           // 64 blocks / batch
  const int unit = ((g & 63) << 8) + threadIdx.x; // uint2 unit 0..16383
  u16* base = A + (size_t)b * ((size_t)C_ * D_ * D_) + (size_t)unit * 4;
  const float* Pb = P + b * C_;

  uint2 d[C_];
#pragma unroll
  for (int c = 0; c < C_; ++c)
    d[c] = *(const uint2*)(base + (size_t)c * (D_ * D_));

  float h0 = 0.f, h1 = 0.f, h2 = 0.f, h3 = 0.f;
#pragma unroll
  for (int c = 0; c < C_; ++c) {
    const float pc = Pb[c];
    const uint2 u = d[c];
    const float a0 = __uint_as_float(u.x << 16);
    const float a1 = __uint_as_float(u.x & 0xFFFF0000u);
    const float a2 = __uint_as_float(u.y << 16);
    const float a3 = __uint_as_float(u.y & 0xFFFF0000u);
    d[c].x = pk2(h0, h1);
    d[c].y = pk2(h2, h3);
    h0 = fmaf(pc, h0, a0); h1 = fmaf(pc, h1, a1);
    h2 = fmaf(pc, h2, a2); h3 = fmaf(pc, h3, a3);
  }
#pragma unroll
  for (int c = 0; c < C_; ++c)
    *(uint2*)(base + (size_t)c * (D_ * D_)) = d[c];
}

// ---------------------------------------------------------------------------
// Kernel 3: O = Tm @ V + diag(c) Q @ H.   512 thr / 8 waves, L=128.
// Reordered: VT(h0) staged + first H frags preloaded BEFORE the Tm barrier;
// QH loop software-pipelines H loads one k-step ahead.
// ---------------------------------------------------------------------------
__global__ __launch_bounds__(512, 2) void ks_output6(
    const float* __restrict__ qg, const float* __restrict__ kg,
    const float* __restrict__ vg, const float* __restrict__ beta,
    const u16* __restrict__ Hg, float* __restrict__ outg)
{
  __shared__ float ls[L_];
  __shared__ float cv[L_];
  __shared__ __align__(16) u16 QB[L_ * 264];     // [t][d] bf16   (67.6 KB)
  __shared__ __align__(16) u16 Tm[L_ * 136];     // [t][s] bf16   (34.8 KB)
  __shared__ __align__(16) u16 VT[256 * STK];    // [j][s-half]   (33.8 KB)

  const int bc = blockIdx.x;
  const int b = bc / C_, c = bc % C_;
  const int tid = threadIdx.x;
  const float* betap = beta + (size_t)b * S_ + (size_t)c * L_;
  const float* qbase = qg + ((size_t)b * S_ + (size_t)c * L_) * D_;
  const float* kbase = kg + ((size_t)b * S_ + (size_t)c * L_) * D_;
  const float* vbase = vg + ((size_t)b * S_ + (size_t)c * L_) * D_;
  const u16* Hb = Hg + (size_t)bc * D_ * D_;

  beta_scan128(betap, ls, tid);

  // ---- stage QB row-major bf16 ----
  {
    const int t = tid >> 2;
    const int cg = (tid & 3) * 8;
    const float* src = qbase + (size_t)t * D_ + cg;
#pragma unroll
    for (int p = 0; p < 8; ++p) {
      const s8v pk = pack8(*(const float4*)(src + p * 32),
                           *(const float4*)(src + p * 32 + 4));
      *(s8v*)&QB[t * 264 + cg + p * 32] = pk;
    }
  }
  __syncthreads();
  if (tid < L_) cv[tid] = exp2f(ls[tid]);   // c_t

  const int lane = tid & 63, wave = tid >> 6;
  const int quad = lane >> 4, l15 = lane & 15;
  const int j0w = wave * 32;

  // ---- phase A: T = Q K^T.  wave w owns s-tile w; loops all 8 t-tiles ----
  {
    const int mA = wave * 16;           // s-tile base
    f4v accA[8];
#pragma unroll
    for (int i = 0; i < 8; ++i) accA[i] = (f4v){0.f, 0.f, 0.f, 0.f};
#pragma unroll
    for (int kd = 0; kd < 8; ++kd) {
      const int d0 = kd * 32 + quad * 8;
      const float* krow = kbase + (size_t)(mA + l15) * D_ + d0;
      const s8v af = pack8(*(const float4*)krow, *(const float4*)(krow + 4));
#pragma unroll
      for (int nt = 0; nt < 8; ++nt) {
        const s8v bf = *(const s8v*)&QB[(nt * 16 + l15) * 264 + d0];
        accA[nt] = __builtin_amdgcn_mfma_f32_16x16x32_bf16(af, bf, accA[nt],
                                                           0, 0, 0);
      }
    }
    // rows = s (quad*4+r), cols = t (l15): mask+decay, pack s-pairs
#pragma unroll
    for (int nt = 0; nt < 8; ++nt) {
      const int t = nt * 16 + l15;
      const float lt = ls[t];
      const int s0 = mA + quad * 4;
      float v[4];
#pragma unroll
      for (int r = 0; r < 4; ++r) {
        const int s = s0 + r;
        v[r] = (s <= t) ? accA[nt][r] * exp2f(lt - ls[s]) : 0.f;
      }
      uint2 w;
      w.x = pk2(v[0], v[1]);
      w.y = pk2(v[2], v[3]);
      *(uint2*)&Tm[t * 136 + s0] = w;
    }
  }

  // ---- stage VT half 0 (independent of Tm; before the barrier) ----
  {
    const int iL = tid & 15;
    const int s0 = ((tid >> 4) & 31) * 2;
    const float* src0 = vbase + (size_t)s0 * D_;
    const float* src1 = src0 + D_;
#pragma unroll
    for (int p = 0; p < 4; ++p) {
      const int i0 = p * 64 + iL * 4;
      float a0[4], a1[4];
      *(float4*)a0 = *(const float4*)(src0 + i0);
      *(float4*)a1 = *(const float4*)(src1 + i0);
#pragma unroll
      for (int u = 0; u < 4; ++u)
        *(u32*)&VT[(i0 + u) * STK + s0] = pk2(a0[u], a1[u]);
    }
  }

  // preload first H k-step (global, independent of LDS)
  s8v hc[2];
#pragma unroll
  for (int mt = 0; mt < 2; ++mt)
    hc[mt] = *(const s8v*)(Hb + (size_t)(j0w + mt * 16 + l15) * D_ + quad * 8);

  __syncthreads();   // Tm + VT(h0) visible

  // ---- Q @ H into acc, H loads pipelined one step ahead ----
  f4v acc[2][8];
#pragma unroll
  for (int mt = 0; mt < 2; ++mt)
#pragma unroll
    for (int nt = 0; nt < 8; ++nt) acc[mt][nt] = (f4v){0.f, 0.f, 0.f, 0.f};

#pragma unroll
  for (int ks = 0; ks < 8; ++ks) {
    const int io = ks * 32 + quad * 8;
    s8v hn[2] = {hc[0], hc[1]};
    if (ks < 7) {
#pragma unroll
      for (int mt = 0; mt < 2; ++mt)
        hn[mt] = *(const s8v*)(Hb + (size_t)(j0w + mt * 16 + l15) * D_ +
                               io + 32);
    }
    s8v bf[8];
#pragma unroll
    for (int nt = 0; nt < 8; ++nt)
      bf[nt] = *(const s8v*)&QB[(nt * 16 + l15) * 264 + io];
#pragma unroll
    for (int mt = 0; mt < 2; ++mt)
#pragma unroll
      for (int nt = 0; nt < 8; ++nt)
        acc[mt][nt] = __builtin_amdgcn_mfma_f32_16x16x32_bf16(
            hc[mt], bf[nt], acc[mt][nt], 0, 0, 0);
    hc[0] = hn[0]; hc[1] = hn[1];
  }
  // scale by c_t  (t = nt*16 + l15 constant per lane per nt)
#pragma unroll
  for (int nt = 0; nt < 8; ++nt) {
    const float ct = cv[nt * 16 + l15];
#pragma unroll
    for (int mt = 0; mt < 2; ++mt) {
      acc[mt][nt][0] *= ct; acc[mt][nt][1] *= ct;
      acc[mt][nt][2] *= ct; acc[mt][nt][3] *= ct;
    }
  }

  // ---- Tm @ V half 0 (VT already staged) ----
#pragma unroll
  for (int ks = 0; ks < 2; ++ks) {
    const int so = ks * 32 + quad * 8;
    s8v af[2], bf[8];
#pragma unroll
    for (int mt = 0; mt < 2; ++mt)
      af[mt] = *(const s8v*)&VT[(j0w + mt * 16 + l15) * STK + so];
#pragma unroll
    for (int nt = 0; nt < 8; ++nt)
      bf[nt] = *(const s8v*)&Tm[(nt * 16 + l15) * 136 + so];
#pragma unroll
    for (int mt = 0; mt < 2; ++mt)
#pragma unroll
      for (int nt = 0; nt < 8; ++nt)
        acc[mt][nt] = __builtin_amdgcn_mfma_f32_16x16x32_bf16(
            af[mt], bf[nt], acc[mt][nt], 0, 0, 0);
  }

  // ---- Tm @ V half 1: restage VT, then accumulate ----
  __syncthreads();   // all h0 reads done before overwrite
  {
    const int iL = tid & 15;
    const int s0 = ((tid >> 4) & 31) * 2;
    const float* src0 = vbase + (size_t)(64 + s0) * D_;
    const float* src1 = src0 + D_;
#pragma unroll
    for (int p = 0; p < 4; ++p) {
      const int i0 = p * 64 + iL * 4;
      float a0[4], a1[4];
      *(float4*)a0 = *(const float4*)(src0 + i0);
      *(float4*)a1 = *(const float4*)(src1 + i0);
#pragma unroll
      for (int u = 0; u < 4; ++u)
        *(u32*)&VT[(i0 + u) * STK + s0] = pk2(a0[u], a1[u]);
    }
  }
  __syncthreads();
#pragma unroll
  for (int ks = 0; ks < 2; ++ks) {
    const int so = ks * 32 + quad * 8;
    s8v af[2], bf[8];
#pragma unroll
    for (int mt = 0; mt < 2; ++mt)
      af[mt] = *(const s8v*)&VT[(j0w + mt * 16 + l15) * STK + so];
#pragma unroll
    for (int nt = 0; nt < 8; ++nt)
      bf[nt] = *(const s8v*)&Tm[(nt * 16 + l15) * 136 + 64 + so];
#pragma unroll
    for (int mt = 0; mt < 2; ++mt)
#pragma unroll
      for (int nt = 0; nt < 8; ++nt)
        acc[mt][nt] = __builtin_amdgcn_mfma_f32_16x16x32_bf16(
            af[mt], bf[nt], acc[mt][nt], 0, 0, 0);
  }

  // epilogue: float4 stores (r runs along j)
  float* ob = outg + ((size_t)b * S_ + (size_t)c * L_) * D_;
#pragma unroll
  for (int mt = 0; mt < 2; ++mt)
#pragma unroll
    for (int nt = 0; nt < 8; ++nt) {
      const int t = nt * 16 + l15;
      const int j0 = j0w + mt * 16 + quad * 4;
      float4 o;
      o.x = acc[mt][nt][0]; o.y = acc[mt][nt][1];
      o.z = acc[mt][nt][2]; o.w = acc[mt][nt][3];
      *(float4*)(ob + (size_t)t * D_ + j0) = o;
    }
}

// ---------------------------------------------------------------------------
extern "C" void kernel_launch(void* const* d_in, const int* in_sizes, int n_in,
                              void* d_out, int out_size, void* d_ws,
                              size_t ws_size, hipStream_t stream) {
  const float* q = (const float*)d_in[0];
  const float* k = (const float*)d_in[1];
  const float* v = (const float*)d_in[2];
  const float* beta = (const float*)d_in[3];
  float* out = (float*)d_out;

  u16* A = (u16*)d_ws;                                   // 33.5 MB bf16 state
  float* P = (float*)((char*)d_ws + (size_t)BC_ * D_ * D_ * sizeof(u16));

  ks_summary6<<<dim3(BC_), dim3(512), 0, stream>>>(k, v, beta, A, P);
  ks_scan6<<<dim3(512), dim3(256), 0, stream>>>(A, P);
  ks_output6<<<dim3(BC_), dim3(512), 0, stream>>>(q, k, v, beta, A, out);
}